// Round 11
// baseline (439.597 us; speedup 1.0000x reference)
//
#include <hip/hip_runtime.h>
#include <cstdint>
#include <cstddef>

// ---------------------------------------------------------------------------
//   x:    [B=128, T=256, D=1024] fp32  ==  A[32768][1024] row-major (b*256+t)
//   Wk:   [1024, 512] per dir    Wr: [128, 512]    bias: [512]
//   xp[dir][t*128+b][512] = x[b,t,:] @ Wk + bias   (bf16, t-major, bias folded)
//   R11: (a) gemm A-staging conversion via v_cvt_pk_bf16_f32 (16 HW packed
//   converts replace ~96 VALU ops of manual RNE f2b; HW cvt is RNE ->
//   bit-identical xp). (b) lstm MFMA chains broken: 16 independent zero-C
//   MFMAs + scalar add-tree on row-0 element (removes 3 serial MFMA dep
//   latencies from the recurrence critical path; f32 reorder <=1ulp).
//   Everything else frozen at R10.
// ---------------------------------------------------------------------------

typedef __attribute__((ext_vector_type(8))) short short8;
typedef __attribute__((ext_vector_type(4))) float f32x4;
typedef __attribute__((address_space(1))) unsigned int gas_uint;
typedef __attribute__((address_space(3))) unsigned int las_uint;
typedef __attribute__((address_space(1))) const unsigned short as1_us;

__device__ __forceinline__ unsigned short f2b(float f) {
    unsigned int u = __float_as_uint(f);
    u += 0x7FFFu + ((u >> 16) & 1u);          // RNE
    return (unsigned short)(u >> 16);
}
__device__ __forceinline__ float b2f(unsigned short u) {
    return __uint_as_float(((unsigned int)u) << 16);
}
// HW packed f32->bf16 (RNE, same result as f2b pair): lo16=bf16(a), hi16=bf16(b)
__device__ __forceinline__ unsigned int cvt_pk_bf16(float a, float b) {
    unsigned int r;
    asm("v_cvt_pk_bf16_f32 %0, %1, %2" : "=v"(r) : "v"(a), "v"(b));
    return r;
}
// fast activations: v_rcp_f32 instead of exact fp32 division (~1 ulp)
__device__ __forceinline__ float rcp_(float x) { return __builtin_amdgcn_rcpf(x); }
__device__ __forceinline__ float sigmoidf_(float z) { return rcp_(1.0f + __expf(-z)); }
__device__ __forceinline__ float tanhf_(float z) {
    float e = __expf(2.0f * z);
    return 1.0f - 2.0f * rcp_(e + 1.0f);
}

// workgroup barrier WITHOUT the vmcnt(0) drain __syncthreads would emit:
// LDS ordering only — outstanding global prefetch loads stay in flight.
#define LITE_BARRIER() asm volatile("s_waitcnt lgkmcnt(0)\n\ts_barrier" ::: "memory")

// async global->LDS 16B
__device__ __forceinline__ void async_ld16(const unsigned short* g, unsigned short* l) {
    __builtin_amdgcn_global_load_lds(
        (gas_uint*)(uintptr_t)g,
        (las_uint*)(uintptr_t)(unsigned int)(uintptr_t)l,
        16, 0, 0);
}

// ---------------------------------------------------------------------------
// Kernel 1: transpose + convert Wk [1024][512] -> Wk_t [512][1024] bf16
// ---------------------------------------------------------------------------
__global__ void conv_wk(const float* __restrict__ wf, const float* __restrict__ wb,
                        unsigned short* __restrict__ wt) {
    int dir = blockIdx.y;
    const float* w = dir ? wb : wf;
    int id = blockIdx.x * blockDim.x + threadIdx.x;
    int g = id >> 10, d = id & 1023;
    wt[(size_t)dir * 524288 + id] = f2b(w[d * 512 + g]);
}

// ---------------------------------------------------------------------------
// Kernel 2: fused GEMM  xp = bf16(x) @ Wk_t^T + bias -> bf16 t-major
// 128x128 tile, BK=64. A reg-staged from fp32 x with HW cvt_pk_bf16 and
// ds_write into the XOR-swizzled slot; B via global_load_lds w=16.
// Pipelined: B asyncs -> A-prefetch(kt+1) -> vmcnt(8) -> LITE_BARRIER.
// XCD-aware tm grouping kept.
// ---------------------------------------------------------------------------
__global__ __launch_bounds__(256, 2) void gemm_xp(
    const float* __restrict__ X,              // [32768][1024] fp32
    const unsigned short* __restrict__ Wt,
    const float* __restrict__ bf_, const float* __restrict__ bb_,
    unsigned short* __restrict__ XP)
{
    __shared__ unsigned short As[128 * 64];
    __shared__ unsigned short Bs[128 * 64];

    const int tid  = threadIdx.x;

    // ---- XCD-aware decode (bijective: 2048 = 8 xcd * 256 steps) ----
    const int flat = blockIdx.x + 256 * (blockIdx.y + 4 * blockIdx.z);
    const int xcd  = flat & 7;
    const int p    = flat >> 3;
    const int tn   = p & 3;                  // fastest on an XCD
    const int dir  = (p >> 2) & 1;
    const int tm   = xcd * 32 + (p >> 3);    // 32 tms per XCD

    const int w    = tid >> 6;
    const int lane = tid & 63;
    const int lanelo = lane & 15;
    const int quad = lane >> 4;
    const int wm = w & 1, wn = w >> 1;

    const unsigned short* Bmat = Wt + (size_t)dir * 524288;
    const float* bias = dir ? bb_ : bf_;
    unsigned short* out = XP + (size_t)dir * 16777216;

    const float* gax[4];
    const unsigned short* gb[4];
    unsigned short* la[4];                   // per-lane explicit ds_write dest
    unsigned short* lb[4];                   // wave-uniform async dest
#pragma unroll
    for (int c = 0; c < 4; ++c) {
        int p2 = c * 256 + tid;
        int row = p2 >> 3;
        int lc = (p2 & 7) ^ (row & 7);
        gax[c] = X    + (size_t)(tm * 128 + row) * 1024 + lc * 8;
        gb[c]  = Bmat + (size_t)(tn * 128 + row) * 1024 + lc * 8;
        la[c]  = As + (size_t)p2 * 8;
        int ub = (c * 256 + (tid & ~63)) * 8;
        lb[c]  = Bs + ub;
    }

    // prologue: A fp32 prefetch for kt=0
    float4 xr[4][2];
#pragma unroll
    for (int c = 0; c < 4; ++c) {
        xr[c][0] = *(const float4*)(gax[c]);
        xr[c][1] = *(const float4*)(gax[c] + 4);
    }

    f32x4 acc[4][4];
#pragma unroll
    for (int i = 0; i < 4; i++)
#pragma unroll
        for (int j = 0; j < 4; j++) acc[i][j] = (f32x4){0.f, 0.f, 0.f, 0.f};

    for (int kt = 0; kt < 16; ++kt) {
        LITE_BARRIER();                      // WAR: prev iter's ds_reads done
        // stage A: HW packed convert prefetched regs -> bf16 -> swizzled slot
#pragma unroll
        for (int c = 0; c < 4; ++c) {
            uint4 s;
            s.x = cvt_pk_bf16(xr[c][0].x, xr[c][0].y);
            s.y = cvt_pk_bf16(xr[c][0].z, xr[c][0].w);
            s.z = cvt_pk_bf16(xr[c][1].x, xr[c][1].y);
            s.w = cvt_pk_bf16(xr[c][1].z, xr[c][1].w);
            *(uint4*)la[c] = s;
        }
        // B async into LDS (vmcnt-tracked)
#pragma unroll
        for (int c = 0; c < 4; ++c) async_ld16(gb[c] + kt * 64, lb[c]);
        __builtin_amdgcn_sched_barrier(0);   // keep B asyncs ahead of A loads
        if (kt < 15) {
            // A fp32 prefetch for kt+1 — stays in flight across the barrier
#pragma unroll
            for (int c = 0; c < 4; ++c) {
                xr[c][0] = *(const float4*)(gax[c] + (kt + 1) * 64);
                xr[c][1] = *(const float4*)(gax[c] + (kt + 1) * 64 + 4);
            }
            __builtin_amdgcn_sched_barrier(0);
            asm volatile("s_waitcnt vmcnt(8)" ::: "memory");   // B done; 8 A loads fly
        } else {
            asm volatile("s_waitcnt vmcnt(0)" ::: "memory");   // last tile: drain B
        }
        LITE_BARRIER();                      // As ds_writes visible to all waves

#pragma unroll
        for (int ks = 0; ks < 2; ++ks) {
            short8 af[4], bfr[4];
#pragma unroll
            for (int i = 0; i < 4; ++i) {
                int row = wm * 64 + i * 16 + lanelo;
                af[i] = *(const short8*)(As + row * 64 + (((ks * 4 + quad) ^ (row & 7)) * 8));
            }
#pragma unroll
            for (int j = 0; j < 4; ++j) {
                int row = wn * 64 + j * 16 + lanelo;
                bfr[j] = *(const short8*)(Bs + row * 64 + (((ks * 4 + quad) ^ (row & 7)) * 8));
            }
#pragma unroll
            for (int i = 0; i < 4; ++i)
#pragma unroll
                for (int j = 0; j < 4; ++j)
                    acc[i][j] = __builtin_amdgcn_mfma_f32_16x16x32_bf16(af[i], bfr[j], acc[i][j], 0, 0, 0);
        }
    }

    float biasv[4];
#pragma unroll
    for (int j = 0; j < 4; ++j)
        biasv[j] = bias[tn * 128 + wn * 64 + j * 16 + lanelo];

#pragma unroll
    for (int i = 0; i < 4; ++i) {
#pragma unroll
        for (int r = 0; r < 4; ++r) {
            int gr = tm * 128 + wm * 64 + i * 16 + quad * 4 + r;   // = b*256 + t
            int bb = gr >> 8, tt = gr & 255;
            size_t orow = (size_t)(tt * 128 + bb) * 512;
#pragma unroll
            for (int j = 0; j < 4; ++j) {
                int col = tn * 128 + wn * 64 + j * 16 + lanelo;
                out[orow + col] = f2b(acc[i][j][r] + biasv[j]);
            }
        }
    }
}

// ---------------------------------------------------------------------------
// Kernel 3: LSTM recurrence. 256 blocks x 512 thr; block = (dir, seq).
// M=seq orientation (row 0 only real):  A = h [1 x 128], B = Wr [128 x 512].
// Wave w: 4 gate-tiles (N = g*128 + [16w,16w+16)) x 4 k-steps = 16 MFMAs,
// now ALL INDEPENDENT (zero-C each); per-gate K-partials summed by a scalar
// add-tree on element 0 (the only live row) -> no serial MFMA dep chain.
// Quad-0 lanes hold z for all 4 gates of dim (16w+lanelo) -> activation
// in-lane (rcp-fast), h written as 1 b16 LDS store. One lite barrier/step.
// x prefetch depth 4 via address_space(1) loads (vmcnt-only).
// ---------------------------------------------------------------------------
__global__ __launch_bounds__(512, 2) void lstm_rec(
    const unsigned short* __restrict__ XP,    // [2][256*128][512] bf16, bias folded
    const float* __restrict__ Wfr, const float* __restrict__ Wbr,
    float* __restrict__ Hout)                 // [2][128][128]
{
    __shared__ unsigned short h_lds[2][128];  // [buf][dim]

    const int tid    = threadIdx.x;
    const int w      = tid >> 6;              // 0..7
    const int lane   = tid & 63;
    const int lanelo = lane & 15;
    const int quad   = lane >> 4;
    const int dir    = blockIdx.x >> 7;
    const int seq    = blockIdx.x & 127;
    const int dim    = w * 16 + lanelo;       // 0..127

    const float* Wr = dir ? Wbr : Wfr;
    const unsigned short* xp = XP + (size_t)dir * 16777216;

    // --- one-time B-fragments: wrf[g][ks][j] = Wr[ks*32+quad*8+j][g*128+dim]
    short8 wrf[4][4];
#pragma unroll
    for (int g = 0; g < 4; ++g)
#pragma unroll
        for (int ks = 0; ks < 4; ++ks) {
            short8 f;
#pragma unroll
            for (int j = 0; j < 8; ++j)
                f[j] = (short)f2b(Wr[(size_t)(ks * 32 + quad * 8 + j) * 512 + g * 128 + dim]);
            wrf[g][ks] = f;
        }

    if (tid < 128) ((unsigned short*)h_lds)[tid] = 0;   // zero h buffer 0

    // A-fragment of h; only row 0 (lanelo==0 lanes) is real.
    short8 hfrag[4];
    const short8 hz = (short8){0, 0, 0, 0, 0, 0, 0, 0};
#pragma unroll
    for (int ks = 0; ks < 4; ++ks) hfrag[ks] = hz;

    float cv = 0.f, hv = 0.f;

    // x prefetch: explicit address_space(1) loads (vmcnt-only, immune to the
    // lgkmcnt drain in LITE_BARRIER). Depth 4: consume buf, re-load for t+4.
    const ptrdiff_t xstep = dir ? -65536 : 65536;       // elements per t
    const unsigned short* xb_ =
        xp + (size_t)(dir ? 255 : 0) * 65536 + (size_t)seq * 512 + dim;

    unsigned int xA[4], xB[4], xC[4], xD[4];

#define XLOAD(BUF)                                                               \
    {                                                                            \
        const as1_us* xg = (const as1_us*)(uintptr_t)xb_;                        \
        _Pragma("unroll")                                                        \
        for (int g = 0; g < 4; ++g) BUF[g] = xg[g * 128];                        \
        xb_ += xstep;                                                            \
    }

    XLOAD(xA)   // t=0
    XLOAD(xB)   // t=1
    XLOAD(xC)   // t=2
    XLOAD(xD)   // t=3
    // overshoot past the sequence end stays inside the XP allocation
    // (reads the other direction's region; values unused).

    LITE_BARRIER();                           // h_lds[0] zeros visible

    const f32x4 kZ = (f32x4){0.f, 0.f, 0.f, 0.f};

#define MFMA_(A, B) __builtin_amdgcn_mfma_f32_16x16x32_bf16(A, B, kZ, 0, 0, 0)

#define LSTM_STEP(XC_, CUR, NXT)                                                 \
    {                                                                            \
        /* consume x loaded 4 steps ago (long arrived); reissue for t+4 */       \
        float xv0 = b2f((unsigned short)XC_[0]);                                 \
        float xv1 = b2f((unsigned short)XC_[1]);                                 \
        float xv2 = b2f((unsigned short)XC_[2]);                                 \
        float xv3 = b2f((unsigned short)XC_[3]);                                 \
        XLOAD(XC_)                                                               \
        /* masked A-frag read: only row 0 is real */                             \
        if (lanelo == 0) {                                                       \
            _Pragma("unroll")                                                    \
            for (int ks = 0; ks < 4; ++ks)                                       \
                hfrag[ks] = *(const short8*)(&h_lds[CUR][ks * 32 + quad * 8]);   \
        }                                                                        \
        /* 16 INDEPENDENT MFMAs (zero-C); K-partials summed on elem 0 */         \
        f32x4 p0a = MFMA_(hfrag[0], wrf[0][0]), p0b = MFMA_(hfrag[1], wrf[0][1]);\
        f32x4 p0c = MFMA_(hfrag[2], wrf[0][2]), p0d = MFMA_(hfrag[3], wrf[0][3]);\
        f32x4 p1a = MFMA_(hfrag[0], wrf[1][0]), p1b = MFMA_(hfrag[1], wrf[1][1]);\
        f32x4 p1c = MFMA_(hfrag[2], wrf[1][2]), p1d = MFMA_(hfrag[3], wrf[1][3]);\
        f32x4 p2a = MFMA_(hfrag[0], wrf[2][0]), p2b = MFMA_(hfrag[1], wrf[2][1]);\
        f32x4 p2c = MFMA_(hfrag[2], wrf[2][2]), p2d = MFMA_(hfrag[3], wrf[2][3]);\
        f32x4 p3a = MFMA_(hfrag[0], wrf[3][0]), p3b = MFMA_(hfrag[1], wrf[3][1]);\
        f32x4 p3c = MFMA_(hfrag[2], wrf[3][2]), p3d = MFMA_(hfrag[3], wrf[3][3]);\
        /* activation: quad-0 lanes own (dim); all gates in-lane */              \
        if (quad == 0) {                                                         \
            float zi = ((p0a[0] + p0b[0]) + (p0c[0] + p0d[0])) + xv0;            \
            float zf = ((p1a[0] + p1b[0]) + (p1c[0] + p1d[0])) + xv1;            \
            float zg = ((p2a[0] + p2b[0]) + (p2c[0] + p2d[0])) + xv2;            \
            float zo = ((p3a[0] + p3b[0]) + (p3c[0] + p3d[0])) + xv3;            \
            float iv = sigmoidf_(zi), fv = sigmoidf_(zf);                        \
            float gv = tanhf_(zg),    ov = sigmoidf_(zo);                        \
            cv = fv * cv + iv * gv;                                              \
            hv = ov * tanhf_(cv);                                                \
            h_lds[NXT][dim] = f2b(hv);                                           \
        }                                                                        \
        LITE_BARRIER();                                                          \
    }

    for (int t = 0; t < 256; t += 4) {
        LSTM_STEP(xA, 0, 1)
        LSTM_STEP(xB, 1, 0)
        LSTM_STEP(xC, 0, 1)
        LSTM_STEP(xD, 1, 0)
    }
#undef LSTM_STEP
#undef MFMA_
#undef XLOAD

    if (quad == 0)
        Hout[(size_t)(dir * 128 + seq) * 128 + dim] = hv;
}

// ---------------------------------------------------------------------------
// Kernel 4: MLP head
// ---------------------------------------------------------------------------
__global__ void mlp_head(const float* __restrict__ Hout,
                         const float* __restrict__ W1, const float* __restrict__ b1,
                         const float* __restrict__ W2, const float* __restrict__ b2,
                         float* __restrict__ out)
{
    __shared__ float y1[32];
    int b = blockIdx.x;
    int j = threadIdx.x;
    const float* hf = Hout + (size_t)b * 128;
    const float* hb = Hout + (size_t)(128 + b) * 128;
    if (j < 32) {
        float acc = b1[j];
        for (int k = 0; k < 128; ++k) acc += hf[k] * W1[k * 32 + j];
        for (int k = 0; k < 128; ++k) acc += hb[k] * W1[(128 + k) * 32 + j];
        y1[j] = fmaxf(acc, 0.0f);
    }
    __syncthreads();
    if (j < 2) {
        float z = b2[j];
        for (int k = 0; k < 32; ++k) z += y1[k] * W2[k * 2 + j];
        out[b * 2 + j] = 1.0f / (1.0f + __expf(-z));
    }
}

// ---------------------------------------------------------------------------
extern "C" void kernel_launch(void* const* d_in, const int* in_sizes, int n_in,
                              void* d_out, int out_size, void* d_ws, size_t ws_size,
                              hipStream_t stream) {
    const float* x    = (const float*)d_in[0];
    const float* Wf_k = (const float*)d_in[1];
    const float* Wf_r = (const float*)d_in[2];
    const float* bf   = (const float*)d_in[3];
    const float* Wb_k = (const float*)d_in[4];
    const float* Wb_r = (const float*)d_in[5];
    const float* bb   = (const float*)d_in[6];
    const float* W1   = (const float*)d_in[7];
    const float* b1   = (const float*)d_in[8];
    const float* W2   = (const float*)d_in[9];
    const float* b2   = (const float*)d_in[10];
    float* out = (float*)d_out;

    char* ws = (char*)d_ws;
    const size_t OFF_WT   = 0;                        //  2,097,152 B
    const size_t OFF_HOUT = 2097152;                  //    131,072 B
    const size_t OFF_XP   = OFF_HOUT + 131072;        // 67,108,864 B (bf16)
    // total workspace: ~69.3 MB

    unsigned short* wt  = (unsigned short*)(ws + OFF_WT);
    float*          ho  = (float*)(ws + OFF_HOUT);
    unsigned short* xpb = (unsigned short*)(ws + OFF_XP);

    conv_wk<<<dim3(2048, 2), dim3(256), 0, stream>>>(Wf_k, Wb_k, wt);
    gemm_xp<<<dim3(256, 4, 2), dim3(256), 0, stream>>>(x, wt, bf, bb, xpb);
    lstm_rec<<<dim3(256), dim3(512), 0, stream>>>(xpb, Wf_r, Wb_r, ho);
    mlp_head<<<dim3(128), dim3(64), 0, stream>>>(ho, W1, b1, W2, b2, out);
}

// Round 12
// 399.592 us; speedup vs baseline: 1.1001x; 1.1001x over previous
//
#include <hip/hip_runtime.h>
#include <cstdint>
#include <cstddef>

// ---------------------------------------------------------------------------
//   x:    [B=128, T=256, D=1024] fp32  ==  A[32768][1024] row-major (b*256+t)
//   Wk:   [1024, 512] per dir    Wr: [128, 512]    bias: [512]
//   xp[dir][t*128+b][512] = x[b,t,:] @ Wk + bias   (bf16, t-major, bias folded)
//   R12: (a) lstm_rec reverted to R10 form (chained MFMAs — R11's chain-break
//   measured -21us: extra adds + 64 VGPRs of live partials beat the removed
//   dep latency). (b) gemm 128x256 output tile (2 tn per block, 1024 blocks):
//   A staged once per kt for TWO B-tiles (halves A-staging work), 12 ds_reads
//   feed 64 MFMAs/kt/wave (vs 8:32), half the barrier executions. Bit-identical
//   accumulation order. cvt_pk staging + XCD grouping kept.
// ---------------------------------------------------------------------------

typedef __attribute__((ext_vector_type(8))) short short8;
typedef __attribute__((ext_vector_type(4))) float f32x4;
typedef __attribute__((address_space(1))) unsigned int gas_uint;
typedef __attribute__((address_space(3))) unsigned int las_uint;
typedef __attribute__((address_space(1))) const unsigned short as1_us;

__device__ __forceinline__ unsigned short f2b(float f) {
    unsigned int u = __float_as_uint(f);
    u += 0x7FFFu + ((u >> 16) & 1u);          // RNE
    return (unsigned short)(u >> 16);
}
__device__ __forceinline__ float b2f(unsigned short u) {
    return __uint_as_float(((unsigned int)u) << 16);
}
// HW packed f32->bf16 (RNE, same result as f2b pair): lo16=bf16(a), hi16=bf16(b)
__device__ __forceinline__ unsigned int cvt_pk_bf16(float a, float b) {
    unsigned int r;
    asm("v_cvt_pk_bf16_f32 %0, %1, %2" : "=v"(r) : "v"(a), "v"(b));
    return r;
}
// fast activations: v_rcp_f32 instead of exact fp32 division (~1 ulp)
__device__ __forceinline__ float rcp_(float x) { return __builtin_amdgcn_rcpf(x); }
__device__ __forceinline__ float sigmoidf_(float z) { return rcp_(1.0f + __expf(-z)); }
__device__ __forceinline__ float tanhf_(float z) {
    float e = __expf(2.0f * z);
    return 1.0f - 2.0f * rcp_(e + 1.0f);
}

// workgroup barrier WITHOUT the vmcnt(0) drain __syncthreads would emit:
// LDS ordering only — outstanding global prefetch loads stay in flight.
#define LITE_BARRIER() asm volatile("s_waitcnt lgkmcnt(0)\n\ts_barrier" ::: "memory")

// async global->LDS 16B
__device__ __forceinline__ void async_ld16(const unsigned short* g, unsigned short* l) {
    __builtin_amdgcn_global_load_lds(
        (gas_uint*)(uintptr_t)g,
        (las_uint*)(uintptr_t)(unsigned int)(uintptr_t)l,
        16, 0, 0);
}

// ---------------------------------------------------------------------------
// Kernel 1: transpose + convert Wk [1024][512] -> Wk_t [512][1024] bf16
// ---------------------------------------------------------------------------
__global__ void conv_wk(const float* __restrict__ wf, const float* __restrict__ wb,
                        unsigned short* __restrict__ wt) {
    int dir = blockIdx.y;
    const float* w = dir ? wb : wf;
    int id = blockIdx.x * blockDim.x + threadIdx.x;
    int g = id >> 10, d = id & 1023;
    wt[(size_t)dir * 524288 + id] = f2b(w[d * 512 + g]);
}

// ---------------------------------------------------------------------------
// Kernel 2: fused GEMM  xp = bf16(x) @ Wk_t^T + bias -> bf16 t-major
// 128x256 tile, BK=64, 1024 blocks. A reg-staged from fp32 x (cvt_pk_bf16 ->
// swizzled ds_write), B (2 tiles) via global_load_lds w=16. Pipelined:
// 8 B asyncs -> 8 A-prefetch loads(kt+1) -> vmcnt(8) -> LITE_BARRIER.
// XCD grouping: 4 consecutive same-XCD blocks share one A-tile via L2.
// ---------------------------------------------------------------------------
__global__ __launch_bounds__(256, 2) void gemm_xp(
    const float* __restrict__ X,              // [32768][1024] fp32
    const unsigned short* __restrict__ Wt,
    const float* __restrict__ bf_, const float* __restrict__ bb_,
    unsigned short* __restrict__ XP)
{
    __shared__ unsigned short As[128 * 64];   // 16 KB
    __shared__ unsigned short Bs[256 * 64];   // 32 KB

    const int tid  = threadIdx.x;

    // ---- XCD-aware decode (bijective: 1024 = 8 xcd * 128 steps) ----
    const int flat = blockIdx.x + 256 * (blockIdx.y + 2 * blockIdx.z);
    const int xcd  = flat & 7;
    const int p    = flat >> 3;               // 0..127
    const int tnp  = p & 1;                   // N half (256 cols) — fastest
    const int dir  = (p >> 1) & 1;
    const int tm   = xcd * 32 + (p >> 2);     // 32 tms per XCD

    const int w    = tid >> 6;                // 0..3
    const int lane = tid & 63;
    const int lanelo = lane & 15;
    const int quad = lane >> 4;
    const int wm = w & 1, wn = w >> 1;        // wm: M half, wn: N half (128 cols)

    const unsigned short* Bmat = Wt + (size_t)dir * 524288;
    const float* bias = dir ? bb_ : bf_;
    unsigned short* out = XP + (size_t)dir * 16777216;

    const float* gax[4];
    unsigned short* la[4];                    // per-lane explicit ds_write dest
    const unsigned short* gb[8];
    unsigned short* lb[8];                    // wave-uniform async dest
#pragma unroll
    for (int c = 0; c < 4; ++c) {
        int p2 = c * 256 + tid;
        int row = p2 >> 3;
        int lc = (p2 & 7) ^ (row & 7);
        gax[c] = X + (size_t)(tm * 128 + row) * 1024 + lc * 8;
        la[c]  = As + (size_t)p2 * 8;
    }
#pragma unroll
    for (int c = 0; c < 8; ++c) {
        int p2 = c * 256 + tid;
        int row = p2 >> 3;                    // 0..255
        int lc = (p2 & 7) ^ (row & 7);
        gb[c] = Bmat + (size_t)(tnp * 256 + row) * 1024 + lc * 8;
        lb[c] = Bs + (size_t)(c * 256 + (tid & ~63)) * 8;
    }

    // prologue: A fp32 prefetch for kt=0
    float4 xr[4][2];
#pragma unroll
    for (int c = 0; c < 4; ++c) {
        xr[c][0] = *(const float4*)(gax[c]);
        xr[c][1] = *(const float4*)(gax[c] + 4);
    }

    f32x4 acc[4][8];
#pragma unroll
    for (int i = 0; i < 4; i++)
#pragma unroll
        for (int j = 0; j < 8; j++) acc[i][j] = (f32x4){0.f, 0.f, 0.f, 0.f};

    for (int kt = 0; kt < 16; ++kt) {
        LITE_BARRIER();                      // WAR: prev iter's ds_reads done
        // stage A: HW packed convert prefetched regs -> bf16 -> swizzled slot
#pragma unroll
        for (int c = 0; c < 4; ++c) {
            uint4 s;
            s.x = cvt_pk_bf16(xr[c][0].x, xr[c][0].y);
            s.y = cvt_pk_bf16(xr[c][0].z, xr[c][0].w);
            s.z = cvt_pk_bf16(xr[c][1].x, xr[c][1].y);
            s.w = cvt_pk_bf16(xr[c][1].z, xr[c][1].w);
            *(uint4*)la[c] = s;
        }
        // B async into LDS (8 calls, vmcnt-tracked)
#pragma unroll
        for (int c = 0; c < 8; ++c) async_ld16(gb[c] + kt * 64, lb[c]);
        __builtin_amdgcn_sched_barrier(0);   // keep B asyncs ahead of A loads
        if (kt < 15) {
            // A fp32 prefetch for kt+1 — stays in flight across the barrier
#pragma unroll
            for (int c = 0; c < 4; ++c) {
                xr[c][0] = *(const float4*)(gax[c] + (kt + 1) * 64);
                xr[c][1] = *(const float4*)(gax[c] + (kt + 1) * 64 + 4);
            }
            __builtin_amdgcn_sched_barrier(0);
            asm volatile("s_waitcnt vmcnt(8)" ::: "memory");   // B done; 8 A loads fly
        } else {
            asm volatile("s_waitcnt vmcnt(0)" ::: "memory");   // last tile: drain B
        }
        LITE_BARRIER();                      // As ds_writes visible to all waves

#pragma unroll
        for (int ks = 0; ks < 2; ++ks) {
            short8 af[4], bfr[8];
#pragma unroll
            for (int i = 0; i < 4; ++i) {
                int row = wm * 64 + i * 16 + lanelo;
                af[i] = *(const short8*)(As + row * 64 + (((ks * 4 + quad) ^ (row & 7)) * 8));
            }
#pragma unroll
            for (int j = 0; j < 8; ++j) {
                int row = wn * 128 + j * 16 + lanelo;
                bfr[j] = *(const short8*)(Bs + row * 64 + (((ks * 4 + quad) ^ (row & 7)) * 8));
            }
#pragma unroll
            for (int i = 0; i < 4; ++i)
#pragma unroll
                for (int j = 0; j < 8; ++j)
                    acc[i][j] = __builtin_amdgcn_mfma_f32_16x16x32_bf16(af[i], bfr[j], acc[i][j], 0, 0, 0);
        }
    }

    float biasv[8];
#pragma unroll
    for (int j = 0; j < 8; ++j)
        biasv[j] = bias[tnp * 256 + wn * 128 + j * 16 + lanelo];

#pragma unroll
    for (int i = 0; i < 4; ++i) {
#pragma unroll
        for (int r = 0; r < 4; ++r) {
            int gr = tm * 128 + wm * 64 + i * 16 + quad * 4 + r;   // = b*256 + t
            int bb = gr >> 8, tt = gr & 255;
            size_t orow = (size_t)(tt * 128 + bb) * 512;
#pragma unroll
            for (int j = 0; j < 8; ++j) {
                int col = tnp * 256 + wn * 128 + j * 16 + lanelo;
                out[orow + col] = f2b(acc[i][j][r] + biasv[j]);
            }
        }
    }
}

// ---------------------------------------------------------------------------
// Kernel 3: LSTM recurrence. 256 blocks x 512 thr; block = (dir, seq).
// M=seq orientation (row 0 only real):  A = h [1 x 128], B = Wr [128 x 512].
// Wave w: 4 gate-tiles (N = g*128 + [16w,16w+16)) x 4 k-steps = 16 MFMAs
// (4 indep chains, depth 4 — R10 form). Quad-0 lanes hold z for all 4 gates
// of dim (16w+lanelo) -> activation in-lane (rcp-fast), h written as 1 b16
// LDS store. One lite barrier per step. x prefetch depth 4.
// ---------------------------------------------------------------------------
__global__ __launch_bounds__(512, 2) void lstm_rec(
    const unsigned short* __restrict__ XP,    // [2][256*128][512] bf16, bias folded
    const float* __restrict__ Wfr, const float* __restrict__ Wbr,
    float* __restrict__ Hout)                 // [2][128][128]
{
    __shared__ unsigned short h_lds[2][128];  // [buf][dim]

    const int tid    = threadIdx.x;
    const int w      = tid >> 6;              // 0..7
    const int lane   = tid & 63;
    const int lanelo = lane & 15;
    const int quad   = lane >> 4;
    const int dir    = blockIdx.x >> 7;
    const int seq    = blockIdx.x & 127;
    const int dim    = w * 16 + lanelo;       // 0..127

    const float* Wr = dir ? Wbr : Wfr;
    const unsigned short* xp = XP + (size_t)dir * 16777216;

    // --- one-time B-fragments: wrf[g][ks][j] = Wr[ks*32+quad*8+j][g*128+dim]
    short8 wrf[4][4];
#pragma unroll
    for (int g = 0; g < 4; ++g)
#pragma unroll
        for (int ks = 0; ks < 4; ++ks) {
            short8 f;
#pragma unroll
            for (int j = 0; j < 8; ++j)
                f[j] = (short)f2b(Wr[(size_t)(ks * 32 + quad * 8 + j) * 512 + g * 128 + dim]);
            wrf[g][ks] = f;
        }

    if (tid < 128) ((unsigned short*)h_lds)[tid] = 0;   // zero h buffer 0

    // A-fragment of h; only row 0 (lanelo==0 lanes) is real.
    short8 hfrag[4];
    const short8 hz = (short8){0, 0, 0, 0, 0, 0, 0, 0};
#pragma unroll
    for (int ks = 0; ks < 4; ++ks) hfrag[ks] = hz;

    float cv = 0.f, hv = 0.f;

    // x prefetch: explicit address_space(1) loads (vmcnt-only, immune to the
    // lgkmcnt drain in LITE_BARRIER). Depth 4: consume buf, re-load for t+4.
    const ptrdiff_t xstep = dir ? -65536 : 65536;       // elements per t
    const unsigned short* xb_ =
        xp + (size_t)(dir ? 255 : 0) * 65536 + (size_t)seq * 512 + dim;

    unsigned int xA[4], xB[4], xC[4], xD[4];

#define XLOAD(BUF)                                                               \
    {                                                                            \
        const as1_us* xg = (const as1_us*)(uintptr_t)xb_;                        \
        _Pragma("unroll")                                                        \
        for (int g = 0; g < 4; ++g) BUF[g] = xg[g * 128];                        \
        xb_ += xstep;                                                            \
    }

    XLOAD(xA)   // t=0
    XLOAD(xB)   // t=1
    XLOAD(xC)   // t=2
    XLOAD(xD)   // t=3
    // overshoot past the sequence end stays inside the XP allocation
    // (reads the other direction's region; values unused).

    LITE_BARRIER();                           // h_lds[0] zeros visible

    const f32x4 kZ = (f32x4){0.f, 0.f, 0.f, 0.f};

#define LSTM_STEP(XC_, CUR, NXT)                                                 \
    {                                                                            \
        /* consume x loaded 4 steps ago (long arrived); reissue for t+4 */       \
        float xv0 = b2f((unsigned short)XC_[0]);                                 \
        float xv1 = b2f((unsigned short)XC_[1]);                                 \
        float xv2 = b2f((unsigned short)XC_[2]);                                 \
        float xv3 = b2f((unsigned short)XC_[3]);                                 \
        XLOAD(XC_)                                                               \
        /* masked A-frag read: only row 0 is real */                             \
        if (lanelo == 0) {                                                       \
            _Pragma("unroll")                                                    \
            for (int ks = 0; ks < 4; ++ks)                                       \
                hfrag[ks] = *(const short8*)(&h_lds[CUR][ks * 32 + quad * 8]);   \
        }                                                                        \
        /* 16 MFMAs: 4 independent gate chains, depth 4 */                       \
        f32x4 z0 = __builtin_amdgcn_mfma_f32_16x16x32_bf16(hfrag[0], wrf[0][0], kZ, 0, 0, 0); \
        f32x4 z1 = __builtin_amdgcn_mfma_f32_16x16x32_bf16(hfrag[0], wrf[1][0], kZ, 0, 0, 0); \
        f32x4 z2 = __builtin_amdgcn_mfma_f32_16x16x32_bf16(hfrag[0], wrf[2][0], kZ, 0, 0, 0); \
        f32x4 z3 = __builtin_amdgcn_mfma_f32_16x16x32_bf16(hfrag[0], wrf[3][0], kZ, 0, 0, 0); \
        _Pragma("unroll")                                                        \
        for (int ks = 1; ks < 4; ++ks) {                                         \
            z0 = __builtin_amdgcn_mfma_f32_16x16x32_bf16(hfrag[ks], wrf[0][ks], z0, 0, 0, 0); \
            z1 = __builtin_amdgcn_mfma_f32_16x16x32_bf16(hfrag[ks], wrf[1][ks], z1, 0, 0, 0); \
            z2 = __builtin_amdgcn_mfma_f32_16x16x32_bf16(hfrag[ks], wrf[2][ks], z2, 0, 0, 0); \
            z3 = __builtin_amdgcn_mfma_f32_16x16x32_bf16(hfrag[ks], wrf[3][ks], z3, 0, 0, 0); \
        }                                                                        \
        /* activation: quad-0 lanes own (dim); all gates in-lane */              \
        if (quad == 0) {                                                         \
            float zi = z0[0] + xv0, zf = z1[0] + xv1;                            \
            float zg = z2[0] + xv2, zo = z3[0] + xv3;                            \
            float iv = sigmoidf_(zi), fv = sigmoidf_(zf);                        \
            float gv = tanhf_(zg),    ov = sigmoidf_(zo);                        \
            cv = fv * cv + iv * gv;                                              \
            hv = ov * tanhf_(cv);                                                \
            h_lds[NXT][dim] = f2b(hv);                                           \
        }                                                                        \
        LITE_BARRIER();                                                          \
    }

    for (int t = 0; t < 256; t += 4) {
        LSTM_STEP(xA, 0, 1)
        LSTM_STEP(xB, 1, 0)
        LSTM_STEP(xC, 0, 1)
        LSTM_STEP(xD, 1, 0)
    }
#undef LSTM_STEP
#undef XLOAD

    if (quad == 0)
        Hout[(size_t)(dir * 128 + seq) * 128 + dim] = hv;
}

// ---------------------------------------------------------------------------
// Kernel 4: MLP head
// ---------------------------------------------------------------------------
__global__ void mlp_head(const float* __restrict__ Hout,
                         const float* __restrict__ W1, const float* __restrict__ b1,
                         const float* __restrict__ W2, const float* __restrict__ b2,
                         float* __restrict__ out)
{
    __shared__ float y1[32];
    int b = blockIdx.x;
    int j = threadIdx.x;
    const float* hf = Hout + (size_t)b * 128;
    const float* hb = Hout + (size_t)(128 + b) * 128;
    if (j < 32) {
        float acc = b1[j];
        for (int k = 0; k < 128; ++k) acc += hf[k] * W1[k * 32 + j];
        for (int k = 0; k < 128; ++k) acc += hb[k] * W1[(128 + k) * 32 + j];
        y1[j] = fmaxf(acc, 0.0f);
    }
    __syncthreads();
    if (j < 2) {
        float z = b2[j];
        for (int k = 0; k < 32; ++k) z += y1[k] * W2[k * 2 + j];
        out[b * 2 + j] = 1.0f / (1.0f + __expf(-z));
    }
}

// ---------------------------------------------------------------------------
extern "C" void kernel_launch(void* const* d_in, const int* in_sizes, int n_in,
                              void* d_out, int out_size, void* d_ws, size_t ws_size,
                              hipStream_t stream) {
    const float* x    = (const float*)d_in[0];
    const float* Wf_k = (const float*)d_in[1];
    const float* Wf_r = (const float*)d_in[2];
    const float* bf   = (const float*)d_in[3];
    const float* Wb_k = (const float*)d_in[4];
    const float* Wb_r = (const float*)d_in[5];
    const float* bb   = (const float*)d_in[6];
    const float* W1   = (const float*)d_in[7];
    const float* b1   = (const float*)d_in[8];
    const float* W2   = (const float*)d_in[9];
    const float* b2   = (const float*)d_in[10];
    float* out = (float*)d_out;

    char* ws = (char*)d_ws;
    const size_t OFF_WT   = 0;                        //  2,097,152 B
    const size_t OFF_HOUT = 2097152;                  //    131,072 B
    const size_t OFF_XP   = OFF_HOUT + 131072;        // 67,108,864 B (bf16)
    // total workspace: ~69.3 MB

    unsigned short* wt  = (unsigned short*)(ws + OFF_WT);
    float*          ho  = (float*)(ws + OFF_HOUT);
    unsigned short* xpb = (unsigned short*)(ws + OFF_XP);

    conv_wk<<<dim3(2048, 2), dim3(256), 0, stream>>>(Wf_k, Wb_k, wt);
    gemm_xp<<<dim3(256, 2, 2), dim3(256), 0, stream>>>(x, wt, bf, bb, xpb);
    lstm_rec<<<dim3(256), dim3(512), 0, stream>>>(xpb, Wf_r, Wb_r, ho);
    mlp_head<<<dim3(128), dim3(64), 0, stream>>>(ho, W1, b1, W2, b2, out);
}